// Round 2
// baseline (303.330 us; speedup 1.0000x reference)
//
#include <hip/hip_runtime.h>
#include <stdint.h>

#define N_PP   8192
#define DIM    16
#define NEDGE  262144
#define LOG2E  1.4426950408889634f

// ---- ws float-unit layout ----
// [0]=nonlink_pp [1]=link_pp [2]=nonlink_ap [3]=link_ap [4]=counter(uint)
// (zeroed by 32B hipMemsetAsync). Data regions from float 512:
#define WS_PSBF  512
#define WS_PBF   (WS_PSBF + 65536)
#define WS_ABF   (WS_PBF  + 65536)
#define WS_X2PS  (WS_ABF  + 65536)
#define WS_Y2P   (WS_X2PS + 8192)
#define WS_Y2A   (WS_Y2P  + 8192)
#define WS_EGC   (WS_Y2A  + 8192)   // exp(gamma_pp[8192+j])
#define WS_EBC   (WS_EGC  + 8192)   // exp(beta_ap[8192+j])
#define WS_GL2   (WS_EBC  + 8192)   // gamma_pp[i]*LOG2E
#define WS_BL2   (WS_GL2  + 8192)   // beta_ap[i]*LOG2E

// Main grid: [0,256) edge blocks (no dependency on staged ws);
// then matrix quanta = (128-col group g, 256-row chunk c = 16 row-tiles).
// ap: 64 groups x 32 chunks = 2048. pp: group g needs ceil((g+1)/2) chunks;
// paired bands: groups {2m,2m+1} each have m+1 chunks -> cum 2*sum = m(m+1).
#define NB_EDGE 256
#define NQ_AP   2048
#define NQ_PP   1056
#define NB_TOT  (NB_EDGE + NQ_AP + NQ_PP)   // 3360

typedef short    bf16x8 __attribute__((ext_vector_type(8)));
typedef float    f32x4  __attribute__((ext_vector_type(4)));
typedef unsigned u32x4  __attribute__((ext_vector_type(4)));

__device__ __forceinline__ float waveReduce(float v) {
#pragma unroll
    for (int off = 32; off > 0; off >>= 1)
        v += __shfl_down(v, off, 64);
    return v;
}

__device__ __forceinline__ unsigned bf16_rne(float f) {
    unsigned u = __builtin_bit_cast(unsigned, f);
    return (u + 0x7FFFu + ((u >> 16) & 1u)) >> 16;
}
__device__ __forceinline__ unsigned packbf2(float a, float b) {
    return bf16_rne(a) | (bf16_rne(b) << 16);
}

// Async global->LDS DMA, 16 B/lane, lane i lands at ldsbase + i*16.
__device__ __forceinline__ void gload_lds(const uint32_t* g, uint32_t* l) {
    __builtin_amdgcn_global_load_lds(
        (const __attribute__((address_space(1))) void*)(uintptr_t)g,
        (__attribute__((address_space(3))) void*)(unsigned)(uintptr_t)l,
        16, 0, 0);
}

// K1: 224 blocks, pure conversion + bias precompute (57344 = 7*8192 threads).
__global__ __launch_bounds__(256) void pre_kernel(
    const float* __restrict__ p_star, const float* __restrict__ p,
    const float* __restrict__ a, const float* __restrict__ beta_ap,
    const float* __restrict__ gamma_pp, float* __restrict__ ws)
{
    const int g = blockIdx.x * 256 + threadIdx.x;
    if (g < 3 * 8192) {
        const int arr = g >> 13, idx = g & 8191;
        const float* src = arr == 0 ? p_star : (arr == 1 ? p : a);
        const int bfo = arr == 0 ? WS_PSBF : (arr == 1 ? WS_PBF : WS_ABF);
        const int n2o = arr == 0 ? WS_X2PS : (arr == 1 ? WS_Y2P : WS_Y2A);
        const float4* rp = (const float4*)(src + idx * DIM);
        float4 f0 = rp[0], f1 = rp[1], f2 = rp[2], f3 = rp[3];
        float n2 = f0.x*f0.x + f0.y*f0.y + f0.z*f0.z + f0.w*f0.w
                 + f1.x*f1.x + f1.y*f1.y + f1.z*f1.z + f1.w*f1.w
                 + f2.x*f2.x + f2.y*f2.y + f2.z*f2.z + f2.w*f2.w
                 + f3.x*f3.x + f3.y*f3.y + f3.z*f3.z + f3.w*f3.w;
        u32x4 u0 = { packbf2(f0.x, f0.y), packbf2(f0.z, f0.w),
                     packbf2(f1.x, f1.y), packbf2(f1.z, f1.w) };
        u32x4 u1 = { packbf2(f2.x, f2.y), packbf2(f2.z, f2.w),
                     packbf2(f3.x, f3.y), packbf2(f3.z, f3.w) };
        u32x4* dst = (u32x4*)(ws + bfo) + idx * 2;   // 32 B/row contiguous
        dst[0] = u0; dst[1] = u1;
        ws[n2o + idx] = n2;
    } else {
        const int h = g - 3 * 8192, q = h >> 13, i = h & 8191;
        if      (q == 0) ws[WS_EGC + i] = __expf(gamma_pp[8192 + i]);
        else if (q == 1) ws[WS_EBC + i] = __expf(beta_ap[8192 + i]);
        else if (q == 2) ws[WS_GL2 + i] = gamma_pp[i] * LOG2E;
        else             ws[WS_BL2 + i] = beta_ap[i] * LOG2E;
    }
}

__global__ __launch_bounds__(256) void main_kernel(
    const float* __restrict__ p_star, const float* __restrict__ p,
    const float* __restrict__ a, const float* __restrict__ beta_ap,
    const float* __restrict__ gamma_pp, const int* __restrict__ edges_pp,
    const int* __restrict__ edges_ap, float* __restrict__ ws,
    float* __restrict__ out)
{
    // sbuf: [0,2048) 16 tiles x 16 rows x 8 u32; [2048,2304) x2; [2304,2560) bias
    __shared__ uint32_t sbuf[2560];
    __shared__ float smred[4];
    const int b = blockIdx.x, tid = threadIdx.x;
    const int wid = tid >> 6, lane = tid & 63;

    if (b < NB_EDGE) {
        // ---------------- edge (link-term) blocks ----------------
        const bool isPPe = (b < 128);
        const int  base  = (isPPe ? b : b - 128) * 2048;
        float sum = 0.f;
#pragma unroll
        for (int k = 0; k < 8; ++k) {
            const int e = base + k * 256 + tid;
            const float* yrow; float bias; int e0;
            if (isPPe) {
                e0 = edges_pp[e];
                const int e1 = edges_pp[NEDGE + e];
                yrow = p + e1 * DIM;
                bias = gamma_pp[e0] + gamma_pp[N_PP + e1];
            } else {
                e0 = edges_ap[e];
                const int e1 = edges_ap[NEDGE + e];
                yrow = a + (e1 - N_PP) * DIM;
                bias = beta_ap[e0] + beta_ap[e1];
            }
            const float4* xp4 = (const float4*)(p_star + e0 * DIM);
            const float4* yp4 = (const float4*)yrow;
            float d2 = 0.f;
#pragma unroll
            for (int kk = 0; kk < 4; ++kk) {
                const float4 xv = xp4[kk], yv = yp4[kk];
                const float dx = xv.x - yv.x, dy = xv.y - yv.y,
                            dz = xv.z - yv.z, dw = xv.w - yv.w;
                d2 += dx*dx + dy*dy + dz*dz + dw*dw;
            }
            sum += bias - __builtin_amdgcn_sqrtf(d2);
        }
        const float wsum = waveReduce(sum);
        if ((tid & 63) == 0) smred[wid] = wsum;
        __syncthreads();
        if (tid == 0)
            atomicAdd(&ws[isPPe ? 1 : 3],
                      smred[0] + smred[1] + smred[2] + smred[3]);
    } else {
        // ---------------- matrix (nonlink-term) blocks ----------------
        const int  b2   = b - NB_EDGE;
        const bool isPP = (b2 >= NQ_AP);
        int g, c;
        if (!isPP) { g = b2 >> 5; c = b2 & 31; }
        else {
            const int qq = b2 - NQ_AP;
            int m = 0;
            while ((m + 1) * (m + 2) <= qq) ++m;   // band: groups 2m, 2m+1
            const int r = qq - m * (m + 1);
            g = 2 * m + r / (m + 1);
            c = r % (m + 1);
        }
        const int t0 = c << 4;                     // global 16-row tile base
        const int quad = lane >> 4, l16 = lane & 15;

        const uint32_t* Xbf = (const uint32_t*)(ws + WS_PSBF);
        const uint32_t* Ybf = (const uint32_t*)(ws + (isPP ? WS_PBF : WS_ABF));
        const float* x2a = ws + WS_X2PS;
        const float* y2  = ws + (isPP ? WS_Y2P : WS_Y2A);
        const float* gl2 = ws + (isPP ? WS_GL2 : WS_BL2);
        const float* EcA = ws + (isPP ? WS_EGC : WS_EBC);

        // ---- per-wave: two adjacent 16-col strips ----
        const int sA = (g << 3) + (wid << 1);
        bf16x8 bfrag[2];
        float  y2c[2], Ec[2];
#pragma unroll
        for (int ss = 0; ss < 2; ++ss) {
            const int j = ((sA + ss) << 4) + l16;
            u32x4 bu = {0u, 0u, 0u, 0u};
            if (quad < 2) bu = *(const u32x4*)(Ybf + j * 8 + (quad << 2));
            bfrag[ss] = __builtin_bit_cast(bf16x8, bu);
            y2c[ss] = y2[j];
            Ec[ss]  = EcA[j];
        }

        // ---- stage 16 tiles (8 KB rows + 1 KB x2 + 1 KB bias), async DMA ----
        for (int k = wid; k < 10; k += 4) {
            const uint32_t* gsrc;
            int loff;
            if (k < 8)       { gsrc = Xbf + (c << 11) + (k << 8); loff = k << 8; }
            else if (k == 8) { gsrc = (const uint32_t*)(x2a + (c << 8)); loff = 2048; }
            else             { gsrc = (const uint32_t*)(gl2 + (c << 8)); loff = 2304; }
            gload_lds(gsrc + (lane << 2), &sbuf[loff]);
        }
        __syncthreads();   // drains DMA, staging visible

        const f32x4 zero4 = {0.f, 0.f, 0.f, 0.f};
        float acc[2] = {0.f, 0.f};
        const int tEnd = t0 + 16;
        const int tHi  = isPP ? (sA + 2 < tEnd ? sA + 2 : tEnd) : tEnd;
        for (int t = t0; t < tHi; ++t) {
            const int tl = t - t0;
            // aliased unconditional b128: quads 2,3 re-read quads 0,1's valid
            // finite data; it multiplies bfrag's zero upper half -> contributes 0.
            const u32x4 au = *(const u32x4*)&sbuf[(tl << 7) + (l16 << 3) + ((quad & 1) << 2)];
            const f32x4 x24 = *(const f32x4*)((const float*)sbuf + 2048 + (tl << 4) + (quad << 2));
            const f32x4 ag4 = *(const f32x4*)((const float*)sbuf + 2304 + (tl << 4) + (quad << 2));
#pragma unroll
            for (int ss = 0; ss < 2; ++ss) {
                const int s = sA + ss;
                if (isPP && t > s) continue;            // wave-uniform
                f32x4 d = __builtin_amdgcn_mfma_f32_16x16x32_bf16(
                    __builtin_bit_cast(bf16x8, au), bfrag[ss], zero4, 0, 0, 0);
                if (!isPP || t < s) {                   // full tile
#pragma unroll
                    for (int r = 0; r < 4; ++r) {
                        float d2 = fmaf(-2.f, d[r], x24[r] + y2c[ss]);
                        d2 = fmaxf(d2, 0.f);
                        acc[ss] += __builtin_amdgcn_exp2f(
                            fmaf(-LOG2E, __builtin_amdgcn_sqrtf(d2), ag4[r]));
                    }
                } else {                                // diagonal tile, strict j>i
#pragma unroll
                    for (int r = 0; r < 4; ++r) {
                        float d2 = fmaf(-2.f, d[r], x24[r] + y2c[ss]);
                        d2 = fmaxf(d2, 0.f);
                        float term = __builtin_amdgcn_exp2f(
                            fmaf(-LOG2E, __builtin_amdgcn_sqrtf(d2), ag4[r]));
                        if (l16 <= (quad << 2) + r) term = 0.f;
                        acc[ss] += term;
                    }
                }
            }
        }
        const float val = acc[0] * Ec[0] + acc[1] * Ec[1];

        const float wsum = waveReduce(val);
        if ((tid & 63) == 0) smred[wid] = wsum;
        __syncthreads();
        if (tid == 0)
            atomicAdd(&ws[isPP ? 0 : 2],
                      smred[0] + smred[1] + smred[2] + smred[3]);
    }

    // ---------------- completion + final reduction ----------------
    __threadfence();
    if (tid == 0) {
        const unsigned old = atomicAdd((unsigned*)(ws + 4), 1u);
        if (old == NB_TOT - 1) {
            const float s0 = atomicAdd(&ws[0], 0.f);   // nonlink_pp
            const float l1 = atomicAdd(&ws[1], 0.f);   // link_pp
            const float s2 = atomicAdd(&ws[2], 0.f);   // nonlink_ap
            const float l3 = atomicAdd(&ws[3], 0.f);   // link_ap
            out[0] = 0.5f * ((s0 - l1) + (s2 - l3)) / (float)N_PP;
        }
    }
}

extern "C" void kernel_launch(void* const* d_in, const int* in_sizes, int n_in,
                              void* d_out, int out_size, void* d_ws, size_t ws_size,
                              hipStream_t stream) {
    const float* p_star   = (const float*)d_in[0];
    const float* p        = (const float*)d_in[1];
    const float* a        = (const float*)d_in[2];
    const float* beta_ap  = (const float*)d_in[3];
    const float* gamma_pp = (const float*)d_in[4];
    const int*   edges_pp = (const int*)d_in[5];
    const int*   edges_ap = (const int*)d_in[6];

    float* ws  = (float*)d_ws;
    float* out = (float*)d_out;

    hipMemsetAsync(d_ws, 0, 32, stream);
    hipLaunchKernelGGL(pre_kernel, dim3(224), dim3(256), 0, stream,
                       p_star, p, a, beta_ap, gamma_pp, ws);
    hipLaunchKernelGGL(main_kernel, dim3(NB_TOT), dim3(256), 0, stream,
                       p_star, p, a, beta_ap, gamma_pp, edges_pp, edges_ap,
                       ws, out);
}

// Round 3
// 202.587 us; speedup vs baseline: 1.4973x; 1.4973x over previous
//
#include <hip/hip_runtime.h>
#include <stdint.h>

#define N_PP   8192
#define DIM    16
#define NEDGE  262144
#define LOG2E  1.4426950408889634f

// ---- ws float-unit layout ----
// [0]=nonlink_pp [1]=link_pp [2]=nonlink_ap [3]=link_ap [4]=counter(uint)
// (zeroed by pre_kernel). Data regions from float 512:
#define WS_PSBF  512
#define WS_PBF   (WS_PSBF + 65536)
#define WS_ABF   (WS_PBF  + 65536)
#define WS_X2PS  (WS_ABF  + 65536)
#define WS_Y2P   (WS_X2PS + 8192)
#define WS_Y2A   (WS_Y2P  + 8192)
#define WS_EGC   (WS_Y2A  + 8192)   // exp(gamma_pp[8192+j])
#define WS_EBC   (WS_EGC  + 8192)   // exp(beta_ap[8192+j])
#define WS_GL2   (WS_EBC  + 8192)   // gamma_pp[i]*LOG2E
#define WS_BL2   (WS_GL2  + 8192)   // beta_ap[i]*LOG2E

// Main grid: [0,256) edge blocks (read only raw inputs, no ws dependency);
// then matrix quanta = (128-col group g, 32-tile chunk c of 512 rows).
// ap: 64 groups x 16 chunks = 1024. pp: group g needs (g>>2)+1 chunks -> 544.
#define NB_EDGE 256
#define NQ_AP   1024
#define NQ_PP   544
#define NB_TOT  (NB_EDGE + NQ_AP + NQ_PP)   // 1824

typedef short    bf16x8 __attribute__((ext_vector_type(8)));
typedef float    f32x4  __attribute__((ext_vector_type(4)));
typedef unsigned u32x4  __attribute__((ext_vector_type(4)));

__device__ __forceinline__ float waveReduce(float v) {
#pragma unroll
    for (int off = 32; off > 0; off >>= 1)
        v += __shfl_down(v, off, 64);
    return v;
}

__device__ __forceinline__ unsigned bf16_rne(float f) {
    unsigned u = __builtin_bit_cast(unsigned, f);
    return (u + 0x7FFFu + ((u >> 16) & 1u)) >> 16;
}
__device__ __forceinline__ unsigned packbf2(float a, float b) {
    return bf16_rne(a) | (bf16_rne(b) << 16);
}

// Async global->LDS DMA, 16 B/lane, lane i lands at ldsbase + i*16.
__device__ __forceinline__ void gload_lds(const uint32_t* g, uint32_t* l) {
    __builtin_amdgcn_global_load_lds(
        (const __attribute__((address_space(1))) void*)(uintptr_t)g,
        (__attribute__((address_space(3))) void*)(unsigned)(uintptr_t)l,
        16, 0, 0);
}

// K1: 224 blocks, pure conversion + bias precompute (57344 = 7*8192 threads).
__global__ __launch_bounds__(256) void pre_kernel(
    const float* __restrict__ p_star, const float* __restrict__ p,
    const float* __restrict__ a, const float* __restrict__ beta_ap,
    const float* __restrict__ gamma_pp, float* __restrict__ ws)
{
    const int g = blockIdx.x * 256 + threadIdx.x;
    if (g < 8) ws[g] = 0.0f;
    if (g < 3 * 8192) {
        const int arr = g >> 13, idx = g & 8191;
        const float* src = arr == 0 ? p_star : (arr == 1 ? p : a);
        const int bfo = arr == 0 ? WS_PSBF : (arr == 1 ? WS_PBF : WS_ABF);
        const int n2o = arr == 0 ? WS_X2PS : (arr == 1 ? WS_Y2P : WS_Y2A);
        const float4* rp = (const float4*)(src + idx * DIM);
        float4 f0 = rp[0], f1 = rp[1], f2 = rp[2], f3 = rp[3];
        float n2 = f0.x*f0.x + f0.y*f0.y + f0.z*f0.z + f0.w*f0.w
                 + f1.x*f1.x + f1.y*f1.y + f1.z*f1.z + f1.w*f1.w
                 + f2.x*f2.x + f2.y*f2.y + f2.z*f2.z + f2.w*f2.w
                 + f3.x*f3.x + f3.y*f3.y + f3.z*f3.z + f3.w*f3.w;
        u32x4 u0 = { packbf2(f0.x, f0.y), packbf2(f0.z, f0.w),
                     packbf2(f1.x, f1.y), packbf2(f1.z, f1.w) };
        u32x4 u1 = { packbf2(f2.x, f2.y), packbf2(f2.z, f2.w),
                     packbf2(f3.x, f3.y), packbf2(f3.z, f3.w) };
        u32x4* dst = (u32x4*)(ws + bfo) + idx * 2;   // 32 B/row contiguous
        dst[0] = u0; dst[1] = u1;
        ws[n2o + idx] = n2;
    } else {
        const int h = g - 3 * 8192, q = h >> 13, i = h & 8191;
        if      (q == 0) ws[WS_EGC + i] = __expf(gamma_pp[8192 + i]);
        else if (q == 1) ws[WS_EBC + i] = __expf(beta_ap[8192 + i]);
        else if (q == 2) ws[WS_GL2 + i] = gamma_pp[i] * LOG2E;
        else             ws[WS_BL2 + i] = beta_ap[i] * LOG2E;
    }
}

// __launch_bounds__(256, 7): force VGPR <= 73 so the edge path cannot poison
// the matrix blocks' LDS-bound residency (7 blocks/CU, as in the 57us config).
__global__ __launch_bounds__(256, 7) void main_kernel(
    const float* __restrict__ p_star, const float* __restrict__ p,
    const float* __restrict__ a, const float* __restrict__ beta_ap,
    const float* __restrict__ gamma_pp, const int* __restrict__ edges_pp,
    const int* __restrict__ edges_ap, float* __restrict__ ws,
    float* __restrict__ out)
{
    // sbuf: [0,4096) 32 tiles x 16 rows x 8 u32; [4096,4608) x2; [4608,5120) bias
    __shared__ uint32_t sbuf[5120];
    __shared__ float smred[4];
    const int b = blockIdx.x, tid = threadIdx.x;
    const int wid = tid >> 6, lane = tid & 63;

    if (b < NB_EDGE) {
        // ---------------- edge (link-term) blocks ----------------
        const bool isPPe = (b < 128);
        const int  base  = (isPPe ? b : b - 128) * 2048;
        float sum = 0.f;
#pragma unroll 1
        for (int k = 0; k < 8; ++k) {
            const int e = base + k * 256 + tid;
            const float* yrow; float bias; int e0;
            if (isPPe) {
                e0 = edges_pp[e];
                const int e1 = edges_pp[NEDGE + e];
                yrow = p + e1 * DIM;
                bias = gamma_pp[e0] + gamma_pp[N_PP + e1];
            } else {
                e0 = edges_ap[e];
                const int e1 = edges_ap[NEDGE + e];
                yrow = a + (e1 - N_PP) * DIM;
                bias = beta_ap[e0] + beta_ap[e1];
            }
            const float4* xp4 = (const float4*)(p_star + e0 * DIM);
            const float4* yp4 = (const float4*)yrow;
            float d2 = 0.f;
#pragma unroll
            for (int kk = 0; kk < 4; ++kk) {
                const float4 xv = xp4[kk], yv = yp4[kk];
                const float dx = xv.x - yv.x, dy = xv.y - yv.y,
                            dz = xv.z - yv.z, dw = xv.w - yv.w;
                d2 += dx*dx + dy*dy + dz*dz + dw*dw;
            }
            sum += bias - __builtin_amdgcn_sqrtf(d2);
        }
        const float wsum = waveReduce(sum);
        if ((tid & 63) == 0) smred[wid] = wsum;
        __syncthreads();
        if (tid == 0)
            atomicAdd(&ws[isPPe ? 1 : 3],
                      smred[0] + smred[1] + smred[2] + smred[3]);
    } else {
        // ---------------- matrix (nonlink-term) blocks ----------------
        const int  b2   = b - NB_EDGE;
        const bool isPP = (b2 >= NQ_AP);
        int g, c;
        if (!isPP) { g = b2 >> 4; c = b2 & 15; }
        else {
            const int qq = b2 - NQ_AP;
            int bnd = 0;
            while (2 * (bnd + 1) * (bnd + 2) <= qq) ++bnd;   // band: groups 4bnd..4bnd+3
            const int r = qq - 2 * bnd * (bnd + 1);
            g = 4 * bnd + r / (bnd + 1);
            c = r % (bnd + 1);
        }
        const int t0 = c << 5;
        const int quad = lane >> 4, l16 = lane & 15;

        const uint32_t* Xbf = (const uint32_t*)(ws + WS_PSBF);
        const uint32_t* Ybf = (const uint32_t*)(ws + (isPP ? WS_PBF : WS_ABF));
        const float* x2a = ws + WS_X2PS;
        const float* y2  = ws + (isPP ? WS_Y2P : WS_Y2A);
        const float* gl2 = ws + (isPP ? WS_GL2 : WS_BL2);
        const float* EcA = ws + (isPP ? WS_EGC : WS_EBC);

        // ---- per-wave: two adjacent 16-col strips ----
        const int sA = (g << 3) + (wid << 1);
        bf16x8 bfrag[2];
        float  y2c[2], Ec[2];
#pragma unroll
        for (int ss = 0; ss < 2; ++ss) {
            const int j = ((sA + ss) << 4) + l16;
            u32x4 bu = {0u, 0u, 0u, 0u};
            if (quad < 2) bu = *(const u32x4*)(Ybf + j * 8 + (quad << 2));
            bfrag[ss] = __builtin_bit_cast(bf16x8, bu);
            y2c[ss] = y2[j];
            Ec[ss]  = EcA[j];
        }

        // ---- stage 32 tiles (16 KB rows + 2 KB x2 + 2 KB bias), async DMA ----
        for (int k = wid; k < 20; k += 4) {
            const uint32_t* gsrc;
            int loff;
            if (k < 16)      { gsrc = Xbf + (t0 << 7) + (k << 8);            loff = k << 8; }
            else if (k < 18) { gsrc = (const uint32_t*)(x2a + (t0 << 4)) + ((k - 16) << 8);
                               loff = 4096 + ((k - 16) << 8); }
            else             { gsrc = (const uint32_t*)(gl2 + (t0 << 4)) + ((k - 18) << 8);
                               loff = 4608 + ((k - 18) << 8); }
            gload_lds(gsrc + (lane << 2), &sbuf[loff]);
        }
        __syncthreads();   // drains DMA, staging visible

        const f32x4 zero4 = {0.f, 0.f, 0.f, 0.f};
        float acc[2] = {0.f, 0.f};
        const int tHi = isPP ? (sA + 1 < t0 + 32 ? sA + 2 : t0 + 32) : t0 + 32;
        for (int t = t0; t < tHi; ++t) {
            const int tl = t - t0;
            // aliased unconditional b128: quads 2,3 re-read quads 0,1's valid
            // finite data; it multiplies bfrag's zero upper half -> contributes 0.
            const u32x4 au = *(const u32x4*)&sbuf[(tl << 7) + (l16 << 3) + ((quad & 1) << 2)];
            const f32x4 x24 = *(const f32x4*)((const float*)sbuf + 4096 + (tl << 4) + (quad << 2));
            const f32x4 ag4 = *(const f32x4*)((const float*)sbuf + 4608 + (tl << 4) + (quad << 2));
#pragma unroll
            for (int ss = 0; ss < 2; ++ss) {
                const int s = sA + ss;
                if (isPP && t > s) continue;            // wave-uniform
                f32x4 d = __builtin_amdgcn_mfma_f32_16x16x32_bf16(
                    __builtin_bit_cast(bf16x8, au), bfrag[ss], zero4, 0, 0, 0);
                if (!isPP || t < s) {                   // full tile
#pragma unroll
                    for (int r = 0; r < 4; ++r) {
                        float d2 = fmaf(-2.f, d[r], x24[r] + y2c[ss]);
                        d2 = fmaxf(d2, 0.f);
                        acc[ss] += __builtin_amdgcn_exp2f(
                            fmaf(-LOG2E, __builtin_amdgcn_sqrtf(d2), ag4[r]));
                    }
                } else {                                // diagonal tile, strict j>i
#pragma unroll
                    for (int r = 0; r < 4; ++r) {
                        float d2 = fmaf(-2.f, d[r], x24[r] + y2c[ss]);
                        d2 = fmaxf(d2, 0.f);
                        float term = __builtin_amdgcn_exp2f(
                            fmaf(-LOG2E, __builtin_amdgcn_sqrtf(d2), ag4[r]));
                        if (l16 <= (quad << 2) + r) term = 0.f;
                        acc[ss] += term;
                    }
                }
            }
        }
        const float val = acc[0] * Ec[0] + acc[1] * Ec[1];

        const float wsum = waveReduce(val);
        if ((tid & 63) == 0) smred[wid] = wsum;
        __syncthreads();
        if (tid == 0)
            atomicAdd(&ws[isPP ? 0 : 2],
                      smred[0] + smred[1] + smred[2] + smred[3]);
    }

    // ---------------- completion + final reduction ----------------
    __threadfence();
    if (tid == 0) {
        const unsigned old = atomicAdd((unsigned*)(ws + 4), 1u);
        if (old == NB_TOT - 1) {
            const float s0 = atomicAdd(&ws[0], 0.f);   // nonlink_pp
            const float l1 = atomicAdd(&ws[1], 0.f);   // link_pp
            const float s2 = atomicAdd(&ws[2], 0.f);   // nonlink_ap
            const float l3 = atomicAdd(&ws[3], 0.f);   // link_ap
            out[0] = 0.5f * ((s0 - l1) + (s2 - l3)) / (float)N_PP;
        }
    }
}

extern "C" void kernel_launch(void* const* d_in, const int* in_sizes, int n_in,
                              void* d_out, int out_size, void* d_ws, size_t ws_size,
                              hipStream_t stream) {
    const float* p_star   = (const float*)d_in[0];
    const float* p        = (const float*)d_in[1];
    const float* a        = (const float*)d_in[2];
    const float* beta_ap  = (const float*)d_in[3];
    const float* gamma_pp = (const float*)d_in[4];
    const int*   edges_pp = (const int*)d_in[5];
    const int*   edges_ap = (const int*)d_in[6];

    float* ws  = (float*)d_ws;
    float* out = (float*)d_out;

    hipLaunchKernelGGL(pre_kernel, dim3(224), dim3(256), 0, stream,
                       p_star, p, a, beta_ap, gamma_pp, ws);
    hipLaunchKernelGGL(main_kernel, dim3(NB_TOT), dim3(256), 0, stream,
                       p_star, p, a, beta_ap, gamma_pp, edges_pp, edges_ap,
                       ws, out);
}

// Round 4
// 147.973 us; speedup vs baseline: 2.0499x; 1.3691x over previous
//
#include <hip/hip_runtime.h>
#include <stdint.h>

#define N_PP   8192
#define DIM    16
#define NEDGE  262144
#define LOG2E  1.4426950408889634f

// ---- ws float-unit layout ----
// [0]=nonlink_pp [1]=link_pp [2]=nonlink_ap [3]=link_ap [4]=counter(uint)
// (zeroed by 32B hipMemsetAsync before pre). Data regions from float 512:
#define WS_PSBF  512
#define WS_PBF   (WS_PSBF + 65536)
#define WS_ABF   (WS_PBF  + 65536)
#define WS_X2PS  (WS_ABF  + 65536)
#define WS_Y2P   (WS_X2PS + 8192)
#define WS_Y2A   (WS_Y2P  + 8192)
#define WS_EGC   (WS_Y2A  + 8192)   // exp(gamma_pp[8192+j])
#define WS_EBC   (WS_EGC  + 8192)   // exp(beta_ap[8192+j])
#define WS_GL2   (WS_EBC  + 8192)   // gamma_pp[i]*LOG2E
#define WS_BL2   (WS_GL2  + 8192)   // beta_ap[i]*LOG2E

// pre grid: [0,1024) edge blocks (512 pp + 512 ap, 512 edges each -> 4
// blocks/CU of latency-hiding, vs 1/CU in the 22us version), then 224
// conversion blocks. main grid: matrix quanta only (the verified 57us
// config) -- fusing edges into main regressed 3x in rounds 1-3.
#define NB_EDGE_PRE 1024
#define NB_CONV     224
#define NB_PRE      (NB_EDGE_PRE + NB_CONV)

// Matrix quanta = (128-col group g, 32-tile chunk c of 512 rows).
// ap: 64 groups x 16 chunks = 1024. pp: group g needs (g>>2)+1 chunks -> 544.
#define NQ_AP  1024
#define NQ_PP  544
#define NB_MAT (NQ_AP + NQ_PP)   // 1568

typedef short    bf16x8 __attribute__((ext_vector_type(8)));
typedef float    f32x4  __attribute__((ext_vector_type(4)));
typedef unsigned u32x4  __attribute__((ext_vector_type(4)));

__device__ __forceinline__ float waveReduce(float v) {
#pragma unroll
    for (int off = 32; off > 0; off >>= 1)
        v += __shfl_down(v, off, 64);
    return v;
}

__device__ __forceinline__ unsigned bf16_rne(float f) {
    unsigned u = __builtin_bit_cast(unsigned, f);
    return (u + 0x7FFFu + ((u >> 16) & 1u)) >> 16;
}
__device__ __forceinline__ unsigned packbf2(float a, float b) {
    return bf16_rne(a) | (bf16_rne(b) << 16);
}

// Async global->LDS DMA, 16 B/lane, lane i lands at ldsbase + i*16.
__device__ __forceinline__ void gload_lds(const uint32_t* g, uint32_t* l) {
    __builtin_amdgcn_global_load_lds(
        (const __attribute__((address_space(1))) void*)(uintptr_t)g,
        (__attribute__((address_space(3))) void*)(unsigned)(uintptr_t)l,
        16, 0, 0);
}

// K1: [0,1024) edge blocks -> atomicAdd link sums into ws[1]/ws[3];
//     [1024,1248) conversion + bias precompute (57344 = 7*8192 threads).
__global__ __launch_bounds__(256) void pre_kernel(
    const float* __restrict__ p_star, const float* __restrict__ p,
    const float* __restrict__ a, const float* __restrict__ beta_ap,
    const float* __restrict__ gamma_pp, const int* __restrict__ edges_pp,
    const int* __restrict__ edges_ap, float* __restrict__ ws)
{
    const int b = blockIdx.x, tid = threadIdx.x;

    if (b < NB_EDGE_PRE) {
        __shared__ float smred[4];
        const bool isPPe = (b < 512);
        const int  base  = (isPPe ? b : b - 512) * 512;
        float sum = 0.f;
#pragma unroll
        for (int k = 0; k < 2; ++k) {
            const int e = base + k * 256 + tid;
            const float* yrow; float bias; int e0;
            if (isPPe) {
                e0 = edges_pp[e];
                const int e1 = edges_pp[NEDGE + e];
                yrow = p + e1 * DIM;
                bias = gamma_pp[e0] + gamma_pp[N_PP + e1];
            } else {
                e0 = edges_ap[e];
                const int e1 = edges_ap[NEDGE + e];
                yrow = a + (e1 - N_PP) * DIM;
                bias = beta_ap[e0] + beta_ap[e1];
            }
            const float4* xp4 = (const float4*)(p_star + e0 * DIM);
            const float4* yp4 = (const float4*)yrow;
            float d2 = 0.f;
#pragma unroll
            for (int kk = 0; kk < 4; ++kk) {
                const float4 xv = xp4[kk], yv = yp4[kk];
                const float dx = xv.x - yv.x, dy = xv.y - yv.y,
                            dz = xv.z - yv.z, dw = xv.w - yv.w;
                d2 += dx*dx + dy*dy + dz*dz + dw*dw;
            }
            sum += bias - __builtin_amdgcn_sqrtf(d2);
        }
        const float wsum = waveReduce(sum);
        if ((tid & 63) == 0) smred[tid >> 6] = wsum;
        __syncthreads();
        if (tid == 0)
            atomicAdd(&ws[isPPe ? 1 : 3],
                      smred[0] + smred[1] + smred[2] + smred[3]);
    } else {
        const int g = (b - NB_EDGE_PRE) * 256 + tid;
        if (g < 3 * 8192) {
            const int arr = g >> 13, idx = g & 8191;
            const float* src = arr == 0 ? p_star : (arr == 1 ? p : a);
            const int bfo = arr == 0 ? WS_PSBF : (arr == 1 ? WS_PBF : WS_ABF);
            const int n2o = arr == 0 ? WS_X2PS : (arr == 1 ? WS_Y2P : WS_Y2A);
            const float4* rp = (const float4*)(src + idx * DIM);
            float4 f0 = rp[0], f1 = rp[1], f2 = rp[2], f3 = rp[3];
            float n2 = f0.x*f0.x + f0.y*f0.y + f0.z*f0.z + f0.w*f0.w
                     + f1.x*f1.x + f1.y*f1.y + f1.z*f1.z + f1.w*f1.w
                     + f2.x*f2.x + f2.y*f2.y + f2.z*f2.z + f2.w*f2.w
                     + f3.x*f3.x + f3.y*f3.y + f3.z*f3.z + f3.w*f3.w;
            u32x4 u0 = { packbf2(f0.x, f0.y), packbf2(f0.z, f0.w),
                         packbf2(f1.x, f1.y), packbf2(f1.z, f1.w) };
            u32x4 u1 = { packbf2(f2.x, f2.y), packbf2(f2.z, f2.w),
                         packbf2(f3.x, f3.y), packbf2(f3.z, f3.w) };
            u32x4* dst = (u32x4*)(ws + bfo) + idx * 2;   // 32 B/row contiguous
            dst[0] = u0; dst[1] = u1;
            ws[n2o + idx] = n2;
        } else if (g < 7 * 8192) {
            const int h = g - 3 * 8192, q = h >> 13, i = h & 8191;
            if      (q == 0) ws[WS_EGC + i] = __expf(gamma_pp[8192 + i]);
            else if (q == 1) ws[WS_EBC + i] = __expf(beta_ap[8192 + i]);
            else if (q == 2) ws[WS_GL2 + i] = gamma_pp[i] * LOG2E;
            else             ws[WS_BL2 + i] = beta_ap[i] * LOG2E;
        }
    }
}

// K2: EXACT round-0 matrix kernel (verified 57us): matrix quanta only.
__global__ void main_kernel(float* __restrict__ ws, float* __restrict__ out)
{
    // sbuf: [0,4096) 32 tiles x 16 rows x 8 u32; [4096,4608) x2; [4608,5120) bias
    __shared__ uint32_t sbuf[5120];
    __shared__ float smred[4];
    const int b = blockIdx.x, tid = threadIdx.x, wid = tid >> 6;
    const int lane = tid & 63, quad = lane >> 4, l16 = lane & 15;

    // ---- decode quantum -> (isPP, group g, chunk c) ----
    const bool isPP = (b >= NQ_AP);
    int g, c;
    if (!isPP) { g = b >> 4; c = b & 15; }
    else {
        const int qq = b - NQ_AP;
        int bnd = 0;
        while (2 * (bnd + 1) * (bnd + 2) <= qq) ++bnd;   // band: groups 4bnd..4bnd+3
        const int r = qq - 2 * bnd * (bnd + 1);
        g = 4 * bnd + r / (bnd + 1);
        c = r % (bnd + 1);
    }
    const int t0 = c << 5;

    const uint32_t* Xbf = (const uint32_t*)(ws + WS_PSBF);
    const uint32_t* Ybf = (const uint32_t*)(ws + (isPP ? WS_PBF : WS_ABF));
    const float* x2a = ws + WS_X2PS;
    const float* y2  = ws + (isPP ? WS_Y2P : WS_Y2A);
    const float* gl2 = ws + (isPP ? WS_GL2 : WS_BL2);
    const float* EcA = ws + (isPP ? WS_EGC : WS_EBC);

    // ---- per-wave: two adjacent 16-col strips ----
    const int sA = (g << 3) + (wid << 1);
    bf16x8 bfrag[2];
    float  y2c[2], Ec[2];
#pragma unroll
    for (int ss = 0; ss < 2; ++ss) {
        const int j = ((sA + ss) << 4) + l16;
        u32x4 bu = {0u, 0u, 0u, 0u};
        if (quad < 2) bu = *(const u32x4*)(Ybf + j * 8 + (quad << 2));
        bfrag[ss] = __builtin_bit_cast(bf16x8, bu);
        y2c[ss] = y2[j];
        Ec[ss]  = EcA[j];
    }

    // ---- stage 32 tiles (16 KB rows + 2 KB x2 + 2 KB bias), async DMA ----
    for (int k = wid; k < 20; k += 4) {
        const uint32_t* gsrc;
        int loff;
        if (k < 16)      { gsrc = Xbf + (t0 << 7) + (k << 8);            loff = k << 8; }
        else if (k < 18) { gsrc = (const uint32_t*)(x2a + (t0 << 4)) + ((k - 16) << 8);
                           loff = 4096 + ((k - 16) << 8); }
        else             { gsrc = (const uint32_t*)(gl2 + (t0 << 4)) + ((k - 18) << 8);
                           loff = 4608 + ((k - 18) << 8); }
        gload_lds(gsrc + (lane << 2), &sbuf[loff]);
    }
    __syncthreads();   // drains DMA, staging visible

    const f32x4 zero4 = {0.f, 0.f, 0.f, 0.f};
    float acc[2] = {0.f, 0.f};
    const int tHi = isPP ? (sA + 1 < t0 + 32 ? sA + 2 : t0 + 32) : t0 + 32;
    for (int t = t0; t < tHi; ++t) {
        const int tl = t - t0;
        // aliased unconditional b128: quads 2,3 re-read quads 0,1's valid
        // finite data; it multiplies bfrag's zero upper half -> contributes 0.
        const u32x4 au = *(const u32x4*)&sbuf[(tl << 7) + (l16 << 3) + ((quad & 1) << 2)];
        const f32x4 x24 = *(const f32x4*)((const float*)sbuf + 4096 + (tl << 4) + (quad << 2));
        const f32x4 ag4 = *(const f32x4*)((const float*)sbuf + 4608 + (tl << 4) + (quad << 2));
#pragma unroll
        for (int ss = 0; ss < 2; ++ss) {
            const int s = sA + ss;
            if (isPP && t > s) continue;            // wave-uniform
            f32x4 d = __builtin_amdgcn_mfma_f32_16x16x32_bf16(
                __builtin_bit_cast(bf16x8, au), bfrag[ss], zero4, 0, 0, 0);
            if (!isPP || t < s) {                   // full tile
#pragma unroll
                for (int r = 0; r < 4; ++r) {
                    float d2 = fmaf(-2.f, d[r], x24[r] + y2c[ss]);
                    d2 = fmaxf(d2, 0.f);
                    acc[ss] += __builtin_amdgcn_exp2f(
                        fmaf(-LOG2E, __builtin_amdgcn_sqrtf(d2), ag4[r]));
                }
            } else {                                // diagonal tile, strict j>i
#pragma unroll
                for (int r = 0; r < 4; ++r) {
                    float d2 = fmaf(-2.f, d[r], x24[r] + y2c[ss]);
                    d2 = fmaxf(d2, 0.f);
                    float term = __builtin_amdgcn_exp2f(
                        fmaf(-LOG2E, __builtin_amdgcn_sqrtf(d2), ag4[r]));
                    if (l16 <= (quad << 2) + r) term = 0.f;
                    acc[ss] += term;
                }
            }
        }
    }
    const float val = acc[0] * Ec[0] + acc[1] * Ec[1];

    float wsum = waveReduce(val);
    if ((tid & 63) == 0) smred[wid] = wsum;
    __syncthreads();
    if (tid == 0) {
        atomicAdd(&ws[isPP ? 0 : 2], smred[0] + smred[1] + smred[2] + smred[3]);
        __threadfence();
        unsigned old = atomicAdd((unsigned*)(ws + 4), 1u);
        if (old == NB_MAT - 1) {
            const float s0 = atomicAdd(&ws[0], 0.f);   // nonlink_pp
            const float l1 = atomicAdd(&ws[1], 0.f);   // link_pp  (from pre)
            const float s2 = atomicAdd(&ws[2], 0.f);   // nonlink_ap
            const float l3 = atomicAdd(&ws[3], 0.f);   // link_ap  (from pre)
            out[0] = 0.5f * ((s0 - l1) + (s2 - l3)) / (float)N_PP;
        }
    }
}

extern "C" void kernel_launch(void* const* d_in, const int* in_sizes, int n_in,
                              void* d_out, int out_size, void* d_ws, size_t ws_size,
                              hipStream_t stream) {
    const float* p_star   = (const float*)d_in[0];
    const float* p        = (const float*)d_in[1];
    const float* a        = (const float*)d_in[2];
    const float* beta_ap  = (const float*)d_in[3];
    const float* gamma_pp = (const float*)d_in[4];
    const int*   edges_pp = (const int*)d_in[5];
    const int*   edges_ap = (const int*)d_in[6];

    float* ws  = (float*)d_ws;
    float* out = (float*)d_out;

    hipMemsetAsync(d_ws, 0, 32, stream);
    hipLaunchKernelGGL(pre_kernel, dim3(NB_PRE), dim3(256), 0, stream,
                       p_star, p, a, beta_ap, gamma_pp, edges_pp, edges_ap, ws);
    hipLaunchKernelGGL(main_kernel, dim3(NB_MAT), dim3(256), 0, stream, ws, out);
}

// Round 5
// 137.196 us; speedup vs baseline: 2.2109x; 1.0786x over previous
//
#include <hip/hip_runtime.h>
#include <stdint.h>

#define N_PP   8192
#define DIM    16
#define NEDGE  262144
#define LOG2E  1.4426950408889634f

// ---- ws float-unit layout ----
// [0]=nonlink_pp [2]=nonlink_ap [4]=counter(uint)
// [8..136)  pp edge per-block sums (pure writes, no init needed)
// [136..264) ap edge per-block sums
// data regions from float 512:
#define WS_EDGE  8
#define WS_PSBF  512
#define WS_PBF   (WS_PSBF + 65536)
#define WS_ABF   (WS_PBF  + 65536)
#define WS_X2PS  (WS_ABF  + 65536)
#define WS_Y2P   (WS_X2PS + 8192)
#define WS_Y2A   (WS_Y2P  + 8192)
#define WS_EGC   (WS_Y2A  + 8192)   // exp(gamma_pp[8192+j])
#define WS_EBC   (WS_EGC  + 8192)   // exp(beta_ap[8192+j])
#define WS_GL2   (WS_EBC  + 8192)   // gamma_pp[i]*LOG2E
#define WS_BL2   (WS_GL2  + 8192)   // beta_ap[i]*LOG2E

// Main grid: one block = one uniform quantum = (col-group g of 128 cols,
// 32-tile chunk c). ap: 64 groups x 16 chunks = 1024. pp: group g needs
// ceil((8g+8)/32) = (g>>2)+1 chunks -> 544. Wave w covers strips 8g+2w, +1.
#define NQ_AP  1024
#define NQ_PP  544
#define NB_MAT (NQ_AP + NQ_PP)

typedef short    bf16x8 __attribute__((ext_vector_type(8)));
typedef float    f32x4  __attribute__((ext_vector_type(4)));
typedef unsigned u32x4  __attribute__((ext_vector_type(4)));

__device__ __forceinline__ float waveReduce(float v) {
#pragma unroll
    for (int off = 32; off > 0; off >>= 1)
        v += __shfl_down(v, off, 64);
    return v;
}

__device__ __forceinline__ unsigned bf16_rne(float f) {
    unsigned u = __builtin_bit_cast(unsigned, f);
    return (u + 0x7FFFu + ((u >> 16) & 1u)) >> 16;
}
__device__ __forceinline__ unsigned packbf2(float a, float b) {
    return bf16_rne(a) | (bf16_rne(b) << 16);
}

// Async global->LDS DMA, 16 B/lane, lane i lands at ldsbase + i*16.
__device__ __forceinline__ void gload_lds(const uint32_t* g, uint32_t* l) {
    __builtin_amdgcn_global_load_lds(
        (const __attribute__((address_space(1))) void*)(uintptr_t)g,
        (__attribute__((address_space(3))) void*)(unsigned)(uintptr_t)l,
        16, 0, 0);
}

// K1: 480 blocks. [0,224): conversions + bias arrays + zero accums.
// [224,480): 256 edge blocks (128 pp + 128 ap, 2048 edges each) -> pure
// per-block writes to ws[WS_EDGE + eb].  (EXACT round-0 version, measured
// twice at ~81.6us total-minus-main; restructures in r1-r4 all regressed.)
__global__ __launch_bounds__(256) void pre_kernel(
    const float* __restrict__ p_star, const float* __restrict__ p,
    const float* __restrict__ a, const float* __restrict__ beta_ap,
    const float* __restrict__ gamma_pp, const int* __restrict__ edges_pp,
    const int* __restrict__ edges_ap, float* __restrict__ ws)
{
    const int b = blockIdx.x, tid = threadIdx.x;

    if (b < 224) {
        const int g = b * 256 + tid;
        if (g < 8) ws[g] = 0.0f;
        if (g < 3 * 8192) {
            const int arr = g >> 13, idx = g & 8191;
            const float* src = arr == 0 ? p_star : (arr == 1 ? p : a);
            const int bfo = arr == 0 ? WS_PSBF : (arr == 1 ? WS_PBF : WS_ABF);
            const int n2o = arr == 0 ? WS_X2PS : (arr == 1 ? WS_Y2P : WS_Y2A);
            const float4* rp = (const float4*)(src + idx * DIM);
            float4 f0 = rp[0], f1 = rp[1], f2 = rp[2], f3 = rp[3];
            float n2 = f0.x*f0.x + f0.y*f0.y + f0.z*f0.z + f0.w*f0.w
                     + f1.x*f1.x + f1.y*f1.y + f1.z*f1.z + f1.w*f1.w
                     + f2.x*f2.x + f2.y*f2.y + f2.z*f2.z + f2.w*f2.w
                     + f3.x*f3.x + f3.y*f3.y + f3.z*f3.z + f3.w*f3.w;
            u32x4 u0 = { packbf2(f0.x, f0.y), packbf2(f0.z, f0.w),
                         packbf2(f1.x, f1.y), packbf2(f1.z, f1.w) };
            u32x4 u1 = { packbf2(f2.x, f2.y), packbf2(f2.z, f2.w),
                         packbf2(f3.x, f3.y), packbf2(f3.z, f3.w) };
            u32x4* dst = (u32x4*)(ws + bfo) + idx * 2;   // 32 B/row contiguous
            dst[0] = u0; dst[1] = u1;
            ws[n2o + idx] = n2;
        } else if (g < 7 * 8192) {
            const int h = g - 3 * 8192, q = h >> 13, i = h & 8191;
            if      (q == 0) ws[WS_EGC + i] = __expf(gamma_pp[8192 + i]);
            else if (q == 1) ws[WS_EBC + i] = __expf(beta_ap[8192 + i]);
            else if (q == 2) ws[WS_GL2 + i] = gamma_pp[i] * LOG2E;
            else             ws[WS_BL2 + i] = beta_ap[i] * LOG2E;
        }
    } else {
        __shared__ float smred[4];
        const int  eb   = b - 224;            // 0..255
        const bool isPP = (eb < 128);
        const int  base = (isPP ? eb : eb - 128) * 2048;
        float sum = 0.f;
#pragma unroll
        for (int k = 0; k < 8; ++k) {
            const int e = base + k * 256 + tid;
            const float* yrow;
            float bias;
            int e0;
            if (isPP) {
                e0 = edges_pp[e];
                int e1 = edges_pp[NEDGE + e];
                yrow = p + e1 * DIM;
                bias = gamma_pp[e0] + gamma_pp[N_PP + e1];
            } else {
                e0 = edges_ap[e];
                int e1 = edges_ap[NEDGE + e];
                yrow = a + (e1 - N_PP) * DIM;
                bias = beta_ap[e0] + beta_ap[e1];
            }
            const float4* xp = (const float4*)(p_star + e0 * DIM);
            const float4* yp = (const float4*)yrow;
            float d2 = 0.f;
#pragma unroll
            for (int kk = 0; kk < 4; ++kk) {
                float4 xv = xp[kk], yv = yp[kk];
                float dx = xv.x - yv.x, dy = xv.y - yv.y,
                      dz = xv.z - yv.z, dw = xv.w - yv.w;
                d2 += dx*dx + dy*dy + dz*dz + dw*dw;
            }
            sum += bias - __builtin_amdgcn_sqrtf(d2);
        }
        float wsum = waveReduce(sum);
        if ((tid & 63) == 0) smred[tid >> 6] = wsum;
        __syncthreads();
        if (tid == 0)
            ws[WS_EDGE + eb] = smred[0] + smred[1] + smred[2] + smred[3];
    }
}

__global__ void main_kernel(float* __restrict__ ws, float* __restrict__ out)
{
    // sbuf: [0,4096) 32 tiles x 16 rows x 8 u32; [4096,4608) x2; [4608,5120) bias
    __shared__ uint32_t sbuf[5120];
    __shared__ float smred[4];
    const int b = blockIdx.x, tid = threadIdx.x, wid = tid >> 6;
    const int lane = tid & 63, quad = lane >> 4, l16 = lane & 15;

    // ---- decode quantum -> (isPP, group g, chunk c) ----
    const bool isPP = (b >= NQ_AP);
    int g, c;
    if (!isPP) { g = b >> 4; c = b & 15; }
    else {
        const int qq = b - NQ_AP;
        int bnd = 0;
        while (2 * (bnd + 1) * (bnd + 2) <= qq) ++bnd;   // band: groups 4bnd..4bnd+3
        const int r = qq - 2 * bnd * (bnd + 1);
        g = 4 * bnd + r / (bnd + 1);
        c = r % (bnd + 1);
    }
    const int t0 = c << 5;

    const uint32_t* Xbf = (const uint32_t*)(ws + WS_PSBF);
    const uint32_t* Ybf = (const uint32_t*)(ws + (isPP ? WS_PBF : WS_ABF));
    const float* x2a = ws + WS_X2PS;
    const float* y2  = ws + (isPP ? WS_Y2P : WS_Y2A);
    const float* gl2 = ws + (isPP ? WS_GL2 : WS_BL2);
    const float* EcA = ws + (isPP ? WS_EGC : WS_EBC);

    // ---- per-wave: two adjacent 16-col strips ----
    const int sA = (g << 3) + (wid << 1);
    bf16x8 bfrag[2];
    float  y2c[2], Ec[2];
#pragma unroll
    for (int ss = 0; ss < 2; ++ss) {
        const int j = ((sA + ss) << 4) + l16;
        u32x4 bu = {0u, 0u, 0u, 0u};
        if (quad < 2) bu = *(const u32x4*)(Ybf + j * 8 + (quad << 2));
        bfrag[ss] = __builtin_bit_cast(bf16x8, bu);
        y2c[ss] = y2[j];
        Ec[ss]  = EcA[j];
    }

    // ---- stage 32 tiles (16 KB rows + 2 KB x2 + 2 KB bias), async DMA ----
    for (int k = wid; k < 20; k += 4) {
        const uint32_t* gsrc;
        int loff;
        if (k < 16)      { gsrc = Xbf + (t0 << 7) + (k << 8);            loff = k << 8; }
        else if (k < 18) { gsrc = (const uint32_t*)(x2a + (t0 << 4)) + ((k - 16) << 8);
                           loff = 4096 + ((k - 16) << 8); }
        else             { gsrc = (const uint32_t*)(gl2 + (t0 << 4)) + ((k - 18) << 8);
                           loff = 4608 + ((k - 18) << 8); }
        gload_lds(gsrc + (lane << 2), &sbuf[loff]);
    }
    __syncthreads();   // drains DMA, staging visible

    const f32x4 zero4 = {0.f, 0.f, 0.f, 0.f};
    float acc[2] = {0.f, 0.f};
    const int tHi = isPP ? (sA + 1 < t0 + 32 ? sA + 2 : t0 + 32) : t0 + 32;

    // LDS byte/word offsets, loop-invariant
    const int aoff  = (l16 << 3) + ((quad & 1) << 2);
    const int foff  = quad << 2;

    // Software-pipelined t-loop: prefetch t+1's LDS reads at the top of
    // iteration t (the ~300cy elementwise phase hides the ds latency), and
    // issue both strips' MFMAs before any elementwise so 16 trans chains
    // run back-to-back while the next loads are in flight.
    u32x4 au_c  = *(const u32x4*)&sbuf[aoff];                          // tl=0
    f32x4 x24_c = *(const f32x4*)((const float*)sbuf + 4096 + foff);
    f32x4 ag4_c = *(const f32x4*)((const float*)sbuf + 4608 + foff);

    for (int t = t0; t < tHi; ++t) {
        const int tln = t - t0 + 1;
        const bool more = (t + 1 < tHi);                // wave-uniform
        u32x4 au_n; f32x4 x24_n, ag4_n;
        if (more) {
            au_n  = *(const u32x4*)&sbuf[(tln << 7) + aoff];
            x24_n = *(const f32x4*)((const float*)sbuf + 4096 + (tln << 4) + foff);
            ag4_n = *(const f32x4*)((const float*)sbuf + 4608 + (tln << 4) + foff);
        }

        // aliased unconditional b128: quads 2,3 re-read quads 0,1's valid
        // finite data; it multiplies bfrag's zero upper half -> contributes 0.
        f32x4 d0, d1;
        const bool a0 = !(isPP && t > sA);
        const bool a1 = !(isPP && t > sA + 1);
        if (a0) d0 = __builtin_amdgcn_mfma_f32_16x16x32_bf16(
                    __builtin_bit_cast(bf16x8, au_c), bfrag[0], zero4, 0, 0, 0);
        if (a1) d1 = __builtin_amdgcn_mfma_f32_16x16x32_bf16(
                    __builtin_bit_cast(bf16x8, au_c), bfrag[1], zero4, 0, 0, 0);

        if (a0) {
            if (!isPP || t < sA) {                      // full tile
#pragma unroll
                for (int r = 0; r < 4; ++r) {
                    float d2 = fmaf(-2.f, d0[r], x24_c[r] + y2c[0]);
                    d2 = fmaxf(d2, 0.f);
                    acc[0] += __builtin_amdgcn_exp2f(
                        fmaf(-LOG2E, __builtin_amdgcn_sqrtf(d2), ag4_c[r]));
                }
            } else {                                    // diagonal, strict j>i
#pragma unroll
                for (int r = 0; r < 4; ++r) {
                    float d2 = fmaf(-2.f, d0[r], x24_c[r] + y2c[0]);
                    d2 = fmaxf(d2, 0.f);
                    float term = __builtin_amdgcn_exp2f(
                        fmaf(-LOG2E, __builtin_amdgcn_sqrtf(d2), ag4_c[r]));
                    if (l16 <= (quad << 2) + r) term = 0.f;
                    acc[0] += term;
                }
            }
        }
        if (a1) {
            if (!isPP || t < sA + 1) {                  // full tile
#pragma unroll
                for (int r = 0; r < 4; ++r) {
                    float d2 = fmaf(-2.f, d1[r], x24_c[r] + y2c[1]);
                    d2 = fmaxf(d2, 0.f);
                    acc[1] += __builtin_amdgcn_exp2f(
                        fmaf(-LOG2E, __builtin_amdgcn_sqrtf(d2), ag4_c[r]));
                }
            } else {                                    // diagonal, strict j>i
#pragma unroll
                for (int r = 0; r < 4; ++r) {
                    float d2 = fmaf(-2.f, d1[r], x24_c[r] + y2c[1]);
                    d2 = fmaxf(d2, 0.f);
                    float term = __builtin_amdgcn_exp2f(
                        fmaf(-LOG2E, __builtin_amdgcn_sqrtf(d2), ag4_c[r]));
                    if (l16 <= (quad << 2) + r) term = 0.f;
                    acc[1] += term;
                }
            }
        }

        if (more) { au_c = au_n; x24_c = x24_n; ag4_c = ag4_n; }
    }
    const float val = acc[0] * Ec[0] + acc[1] * Ec[1];

    float wsum = waveReduce(val);
    if ((tid & 63) == 0) smred[wid] = wsum;
    __syncthreads();
    if (tid == 0) {
        atomicAdd(&ws[isPP ? 2 : 0], smred[0] + smred[1] + smred[2] + smred[3]);
        __threadfence();
        unsigned old = atomicAdd((unsigned*)(ws + 4), 1u);
        if (old == NB_MAT - 1) {
            float s0 = atomicAdd(&ws[0], 0.f);    // nonlink_pp
            float s2 = atomicAdd(&ws[2], 0.f);    // nonlink_ap
            float lpp = 0.f, lap = 0.f;
            for (int i = 0; i < 128; i += 4) {
                const float4 v = *(const float4*)(ws + WS_EDGE + i);
                const float4 u = *(const float4*)(ws + WS_EDGE + 128 + i);
                lpp += v.x + v.y + v.z + v.w;
                lap += u.x + u.y + u.z + u.w;
            }
            out[0] = 0.5f * (s0 - lpp) / (float)N_PP
                   + 0.5f * (s2 - lap) / (float)N_PP;
        }
    }
}

extern "C" void kernel_launch(void* const* d_in, const int* in_sizes, int n_in,
                              void* d_out, int out_size, void* d_ws, size_t ws_size,
                              hipStream_t stream) {
    const float* p_star   = (const float*)d_in[0];
    const float* p        = (const float*)d_in[1];
    const float* a        = (const float*)d_in[2];
    const float* beta_ap  = (const float*)d_in[3];
    const float* gamma_pp = (const float*)d_in[4];
    const int*   edges_pp = (const int*)d_in[5];
    const int*   edges_ap = (const int*)d_in[6];

    float* ws  = (float*)d_ws;
    float* out = (float*)d_out;

    hipLaunchKernelGGL(pre_kernel, dim3(480), dim3(256), 0, stream,
                       p_star, p, a, beta_ap, gamma_pp, edges_pp, edges_ap, ws);
    hipLaunchKernelGGL(main_kernel, dim3(NB_MAT), dim3(256), 0, stream, ws, out);
}